// Round 4
// baseline (958.900 us; speedup 1.0000x reference)
//
#include <hip/hip_runtime.h>
#include <hip/hip_bf16.h>
#include <stdint.h>

using f16 = _Float16;
typedef _Float16 f16x8 __attribute__((ext_vector_type(8)));
typedef float f32x4 __attribute__((ext_vector_type(4)));

static constexpr int HW = 4096;        // H*W
static constexpr int CC = 256;         // channels
static constexpr int ROWS = 131072;    // B*H*W
static constexpr int ACH = 4;          // attention-phase chunks
static constexpr int AROWS = ROWS / ACH;      // 32768 rows / chunk
static constexpr int CWINS = AROWS / 64;      // 512 windows / chunk
static constexpr int SSH = 4;          // shift

// workspace layout (bytes)
static constexpr size_t OFF_WQ = 0;                               // qkv_w f16  768*256
static constexpr size_t OFF_WP = OFF_WQ + (size_t)768*256*2;      // proj_w f16 256*256
static constexpr size_t OFF_W1 = OFF_WP + (size_t)256*256*2;      // fc1_w f16  1024*256
static constexpr size_t OFF_W2 = OFF_W1 + (size_t)1024*256*2;     // fc2_w f16  256*1024
static constexpr size_t OFF_R1 = OFF_W2 + (size_t)256*1024*2;     // 67,108,864 B region
static constexpr size_t OFF_R2 = OFF_R1 + (size_t)ROWS*CC*2;      // 67,108,864 B region
// R1: AW full (131072x256 f16). R2: hwin chunk + Q + K + V; then m_in full.

#define WAITVM(N) asm volatile("s_waitcnt vmcnt(" #N ")" ::: "memory")
#define WAITLGKM  asm volatile("s_waitcnt lgkmcnt(0)" ::: "memory")
#define BAR()     __builtin_amdgcn_s_barrier()

__device__ __forceinline__ void gload16(void* lds, const void* g) {
    __builtin_amdgcn_global_load_lds(
        (const __attribute__((address_space(1))) unsigned int*)g,
        (__attribute__((address_space(3))) unsigned int*)lds, 16, 0, 0);
}

__global__ void k_cvt(const float* __restrict__ s, f16* __restrict__ d, int n) {
    int i = blockIdx.x * 256 + threadIdx.x;
    if (i < n) d[i] = (f16)s[i];
}

// LayerNorm over C=256, dest row (windowed+rolled) gathers from source row of x.
__global__ __launch_bounds__(256) void k_ln(const float* __restrict__ x,
                                            const float* __restrict__ g,
                                            const float* __restrict__ be,
                                            f16* __restrict__ dst, int rowbase) {
    int lrow = blockIdx.x * 4 + (threadIdx.x >> 6);
    int grow = rowbase + lrow;
    int lane = threadIdx.x & 63;
    int n = grow & 63, win = (grow >> 6) & 63, b = grow >> 12;
    int hh  = ((win >> 3) << 3) | (n >> 3);
    int wwc = ((win & 7) << 3) | (n & 7);
    int ho = (hh + SSH) & 63, wo = (wwc + SSH) & 63;
    size_t srow = (size_t)b * HW + ho * 64 + wo;
    float4 v = ((const float4*)(x + srow * CC))[lane];
    float s  = v.x + v.y + v.z + v.w;
    float s2 = v.x*v.x + v.y*v.y + v.z*v.z + v.w*v.w;
#pragma unroll
    for (int off = 32; off; off >>= 1) { s += __shfl_xor(s, off); s2 += __shfl_xor(s2, off); }
    float mean = s * (1.f/256.f);
    float rstd = rsqrtf(s2 * (1.f/256.f) - mean*mean + 1e-5f);
    float4 gv = ((const float4*)g)[lane];
    float4 bv = ((const float4*)be)[lane];
    f16 ob[4];
    ob[0] = (f16)((v.x-mean)*rstd*gv.x + bv.x);
    ob[1] = (f16)((v.y-mean)*rstd*gv.y + bv.y);
    ob[2] = (f16)((v.z-mean)*rstd*gv.z + bv.z);
    ob[3] = (f16)((v.w-mean)*rstd*gv.w + bv.w);
    *(uint2*)(dst + (size_t)lrow * CC + lane * 4) = *(const uint2*)ob;
}

// QKV GEMM: 128x128 tile, BK=32, K=256. Triple-buffered distance-2 prefetch,
// counted vmcnt (never 0 mid-loop), single raw barrier per K-step.
__global__ __launch_bounds__(256) void k_qkv(const f16* __restrict__ A,
                                             const f16* __restrict__ Wt,
                                             const float* __restrict__ bias,
                                             f16* __restrict__ q, f16* __restrict__ kk,
                                             f16* __restrict__ vv) {
    __shared__ f16 As[3 * 128 * 32];
    __shared__ f16 Bs[3 * 128 * 32];
    const int tid = threadIdx.x;
    const int m0 = blockIdx.x * 128, n0 = blockIdx.y * 128;
    const int wave = tid >> 6, lane = tid & 63;
    const int wm = (wave >> 1) * 64, wn = (wave & 1) * 64;
    const int lr = lane & 15, kq = lane >> 4;
    const int i0 = wave * 128 + lane;
    const int r0 = i0 >> 2, c0 = (i0 & 3) * 8;
    const int i1 = i0 + 64;
    const int r1 = i1 >> 2, c1 = (i1 & 3) * 8;
    const int base0 = wave * 1024, base1 = base0 + 512;   // f16 idx within a buffer

    auto stage = [&](int b, int k0) {
        f16* Ab = As + b * 4096; f16* Bb = Bs + b * 4096;
        gload16(&Ab[base0], &A [(size_t)(m0 + r0) * CC + k0 + c0]);
        gload16(&Bb[base0], &Wt[(size_t)(n0 + r0) * CC + k0 + c0]);
        gload16(&Ab[base1], &A [(size_t)(m0 + r1) * CC + k0 + c1]);
        gload16(&Bb[base1], &Wt[(size_t)(n0 + r1) * CC + k0 + c1]);
    };

    f32x4 acc[4][4];
#pragma unroll
    for (int i = 0; i < 4; i++)
#pragma unroll
        for (int j = 0; j < 4; j++) acc[i][j] = f32x4{0.f, 0.f, 0.f, 0.f};

    stage(0, 0);
    stage(1, 32);
#pragma unroll
    for (int s = 0; s < 8; s++) {
        if (s < 7) { WAITVM(4); } else { WAITVM(0); }
        BAR();
        if (s + 2 < 8) stage((s + 2) % 3, (s + 2) * 32);
        const int cb = (s % 3) * 4096;
        f16x8 af[4], bfv[4];
#pragma unroll
        for (int i = 0; i < 4; i++) {
            af[i]  = *(const f16x8*)(&As[cb + (wm + i * 16 + lr) * 32 + kq * 8]);
            bfv[i] = *(const f16x8*)(&Bs[cb + (wn + i * 16 + lr) * 32 + kq * 8]);
        }
#pragma unroll
        for (int mi = 0; mi < 4; mi++)
#pragma unroll
            for (int ni = 0; ni < 4; ni++)
                acc[mi][ni] = __builtin_amdgcn_mfma_f32_16x16x32_f16(af[mi], bfv[ni], acc[mi][ni], 0, 0, 0);
    }

#pragma unroll
    for (int mi = 0; mi < 4; mi++)
#pragma unroll
        for (int ni = 0; ni < 4; ni++)
#pragma unroll
            for (int j = 0; j < 4; j++) {
                int lrow = m0 + wm + mi * 16 + kq * 4 + j;
                int gcol = n0 + wn + ni * 16 + lr;
                float val = acc[mi][ni][j] + bias[gcol];
                int sq = gcol >> 8, h2 = (gcol >> 5) & 7, d = gcol & 31;
                if (sq == 0) val *= 0.1767766952966369f;  // HD^-0.5
                f16* dst = (sq == 0) ? q : (sq == 1 ? kk : vv);
                int winl = lrow >> 6, n = lrow & 63;
                dst[(((size_t)winl * 8 + h2) * 64 + n) * 32 + d] = (f16)val;
            }
}

// proj GEMM, 64 rows x 256 cols/block, fused un-shift+residual->out, LN2->m_out.
// Triple-buffered distance-2 counted-vmcnt pipeline.
__global__ __launch_bounds__(256, 2) void k_proj(const f16* __restrict__ A,
                                                 const f16* __restrict__ Wt,
                                                 const float* __restrict__ bias,
                                                 const float* __restrict__ x_in,
                                                 float* __restrict__ outf,
                                                 f16* __restrict__ m_out,
                                                 const float* __restrict__ g2,
                                                 const float* __restrict__ b2) {
    __shared__ f16 As[3 * 64 * 32];
    __shared__ f16 Bs[3 * 256 * 32];
    __shared__ float rsum[4][64];
    __shared__ float rsq[4][64];
    const int tid = threadIdx.x;
    const int m0 = blockIdx.x * 64;
    const int wave = tid >> 6, lane = tid & 63;
    const int lr = lane & 15, kq = lane >> 4;
    const int ar = tid >> 2, ac = (tid & 3) * 8;

    auto stage = [&](int b, int k0) {
        gload16(&As[b * 2048 + wave * 512], &A[(size_t)(m0 + ar) * CC + k0 + ac]);
#pragma unroll
        for (int r = 0; r < 4; r++)
            gload16(&Bs[b * 8192 + r * 2048 + wave * 512],
                    &Wt[(size_t)(r * 64 + ar) * CC + k0 + ac]);
    };

    f32x4 acc[4][4];
#pragma unroll
    for (int i = 0; i < 4; i++)
#pragma unroll
        for (int j = 0; j < 4; j++) acc[i][j] = f32x4{0.f, 0.f, 0.f, 0.f};

    stage(0, 0);
    stage(1, 32);
#pragma unroll
    for (int s = 0; s < 8; s++) {
        if (s < 7) { WAITVM(5); } else { WAITVM(0); }
        BAR();
        if (s + 2 < 8) stage((s + 2) % 3, (s + 2) * 32);
        const int ca = (s % 3) * 2048, cbb = (s % 3) * 8192;
        f16x8 af[4], bfv[4];
#pragma unroll
        for (int i = 0; i < 4; i++) {
            af[i]  = *(const f16x8*)(&As[ca + (i * 16 + lr) * 32 + kq * 8]);
            bfv[i] = *(const f16x8*)(&Bs[cbb + (wave * 64 + i * 16 + lr) * 32 + kq * 8]);
        }
#pragma unroll
        for (int mi = 0; mi < 4; mi++)
#pragma unroll
            for (int ni = 0; ni < 4; ni++)
                acc[mi][ni] = __builtin_amdgcn_mfma_f32_16x16x32_f16(af[mi], bfv[ni], acc[mi][ni], 0, 0, 0);
    }

    // ---- epilogue: x2 = proj + bias + shortcut -> out; then fused LN2 -> m_out
    int srows[4][4];
#pragma unroll
    for (int mi = 0; mi < 4; mi++)
#pragma unroll
        for (int j = 0; j < 4; j++) {
            int row = m0 + mi * 16 + kq * 4 + j;
            int n = row & 63, win = (row >> 6) & 63, b = row >> 12;
            int hh  = ((win >> 3) << 3) | (n >> 3);
            int wwc = ((win & 7) << 3) | (n & 7);
            int ho = (hh + SSH) & 63, wo = (wwc + SSH) & 63;
            srows[mi][j] = b * HW + ho * 64 + wo;
        }
    float bv[4], gv[4], b2v[4];
#pragma unroll
    for (int ni = 0; ni < 4; ni++) {
        int gcol = wave * 64 + ni * 16 + lr;
        bv[ni] = bias[gcol]; gv[ni] = g2[gcol]; b2v[ni] = b2[gcol];
    }
    float ps[4][4], qs[4][4];
#pragma unroll
    for (int mi = 0; mi < 4; mi++)
#pragma unroll
        for (int j = 0; j < 4; j++) { ps[mi][j] = 0.f; qs[mi][j] = 0.f; }
#pragma unroll
    for (int mi = 0; mi < 4; mi++)
#pragma unroll
        for (int ni = 0; ni < 4; ni++) {
            int gcol = wave * 64 + ni * 16 + lr;
#pragma unroll
            for (int j = 0; j < 4; j++) {
                size_t idx = (size_t)srows[mi][j] * CC + gcol;
                float v = acc[mi][ni][j] + bv[ni] + x_in[idx];
                acc[mi][ni][j] = v;
                outf[idx] = v;
                ps[mi][j] += v; qs[mi][j] += v * v;
            }
        }
#pragma unroll
    for (int off = 1; off < 16; off <<= 1)
#pragma unroll
        for (int mi = 0; mi < 4; mi++)
#pragma unroll
            for (int j = 0; j < 4; j++) {
                ps[mi][j] += __shfl_xor(ps[mi][j], off);
                qs[mi][j] += __shfl_xor(qs[mi][j], off);
            }
    if (lr == 0) {
#pragma unroll
        for (int mi = 0; mi < 4; mi++)
#pragma unroll
            for (int j = 0; j < 4; j++) {
                int rl = mi * 16 + kq * 4 + j;
                rsum[wave][rl] = ps[mi][j];
                rsq[wave][rl]  = qs[mi][j];
            }
    }
    __syncthreads();
    float mean_a[4][4], rstd_a[4][4];
#pragma unroll
    for (int mi = 0; mi < 4; mi++)
#pragma unroll
        for (int j = 0; j < 4; j++) {
            int rl = mi * 16 + kq * 4 + j;
            float s  = rsum[0][rl] + rsum[1][rl] + rsum[2][rl] + rsum[3][rl];
            float s2 = rsq[0][rl] + rsq[1][rl] + rsq[2][rl] + rsq[3][rl];
            float mean = s * (1.f/256.f);
            float var  = s2 * (1.f/256.f) - mean * mean;
            mean_a[mi][j] = mean;
            rstd_a[mi][j] = rsqrtf(var + 1e-5f);
        }
#pragma unroll
    for (int mi = 0; mi < 4; mi++)
#pragma unroll
        for (int ni = 0; ni < 4; ni++) {
            int gcol = wave * 64 + ni * 16 + lr;
#pragma unroll
            for (int j = 0; j < 4; j++) {
                float m = (acc[mi][ni][j] - mean_a[mi][j]) * rstd_a[mi][j] * gv[ni] + b2v[ni];
                m_out[(size_t)srows[mi][j] * CC + gcol] = (f16)m;
            }
        }
}

// Fused MLP: out += fc2(gelu(fc1(m_in))) per 64-row slab.
// LDS: h[64][1024] f16 (XOR-swizzled, 128KB) + 3x8KB W-stage. A-frags in regs.
// fc2 operand-swapped (A:=w2, B:=h) so h is read as contiguous B-frags and the
// f32 output coalesces into 64B segments.
__global__ __launch_bounds__(256) void k_mlp(const f16* __restrict__ A,
                                             const f16* __restrict__ w1,
                                             const f16* __restrict__ w2,
                                             const float* __restrict__ fb1,
                                             const float* __restrict__ fb2,
                                             float* __restrict__ out) {
    extern __shared__ char smem[];                 // [0,131072) h ; [131072,+24576) wst
    char* wst = smem + 131072;
    const int tid = threadIdx.x, wave = tid >> 6, lane = tid & 63;
    const int lc = lane & 15, kq = lane >> 4;
    const int m0 = blockIdx.x * 64;

    // stage A (64x256 f16) into h area; source pre-swizzled so logical byte =
    // row*512 + (colbyte ^ ((row&7)<<4))
#pragma unroll
    for (int i = 0; i < 8; i++) {
        int c0 = (wave * 8 + i) * 64;
        int c = c0 + lane;
        int row = c >> 5, sl = c & 31;
        int cs = sl ^ (row & 7);
        gload16(smem + (size_t)c0 * 16, &A[(size_t)(m0 + row) * 256 + cs * 8]);
    }
    // W stage: 128 rows x 32 f16 tile (8KB), source pre-swizzled (row&3 slots)
    auto stg = [&](int s) {
        int b = s % 3;
        const f16* W; int rb, ks, ldk;
        if (s < 64) { W = w1; rb = (s >> 3) * 128; ks = s & 7; ldk = 256; }
        else { int t = s - 64; W = w2; rb = (t >> 5) * 128; ks = t & 31; ldk = 1024; }
#pragma unroll
        for (int i = 0; i < 2; i++) {
            int c0 = (wave * 2 + i) * 64;
            int c = c0 + lane;
            int row = c >> 2, sl = c & 3;
            int cs = sl ^ (row & 3);
            gload16(wst + b * 8192 + (size_t)c0 * 16,
                    &W[(size_t)(rb + row) * ldk + ks * 32 + cs * 8]);
        }
    };
    stg(0); stg(1);
    WAITVM(4);        // A staged (stg0/stg1's 4 loads may remain in flight)
    BAR();
    f16x8 af[4][8];   // A-frags: 128 VGPR
#pragma unroll
    for (int mi = 0; mi < 4; mi++)
#pragma unroll
        for (int kf = 0; kf < 8; kf++) {
            int row = mi * 16 + lc;
            int byte = row * 512 + ((kf * 64 + kq * 16) ^ ((row & 7) << 4));
            af[mi][kf] = *(const f16x8*)(smem + byte);
        }
    WAITLGKM;
    BAR();            // all waves hold A; h region free for writes

    f32x4 acc[8];
    // ---- fc1: h[64][nb*128..] = gelu(A @ w1^T + b1) ----
    for (int nb = 0; nb < 8; nb++) {
#pragma unroll
        for (int i = 0; i < 8; i++) acc[i] = f32x4{0.f, 0.f, 0.f, 0.f};
#pragma unroll
        for (int ks = 0; ks < 8; ks++) {
            int s = nb * 8 + ks;
            WAITVM(2);
            BAR();
            if (s + 2 < 128) stg(s + 2);
            char* cb = wst + (s % 3) * 8192;
            f16x8 bf[2];
#pragma unroll
            for (int ni = 0; ni < 2; ni++) {
                int row = wave * 32 + ni * 16 + lc;
                bf[ni] = *(const f16x8*)(cb + row * 64 + ((kq * 16) ^ ((row & 3) << 4)));
            }
#pragma unroll
            for (int mi = 0; mi < 4; mi++)
#pragma unroll
                for (int ni = 0; ni < 2; ni++)
                    acc[mi * 2 + ni] = __builtin_amdgcn_mfma_f32_16x16x32_f16(
                        af[mi][ks], bf[ni], acc[mi * 2 + ni], 0, 0, 0);
        }
#pragma unroll
        for (int ni = 0; ni < 2; ni++) {
            int col = nb * 128 + wave * 32 + ni * 16 + lc;
            float bb = fb1[col];
#pragma unroll
            for (int mi = 0; mi < 4; mi++)
#pragma unroll
                for (int j = 0; j < 4; j++) {
                    float v = acc[mi * 2 + ni][j] + bb;
                    float z = 0.7978845608028654f * (v + 0.044715f * v * v * v);
                    float t = 1.f - 2.f / (__expf(2.f * z) + 1.f);
                    float gl = 0.5f * v * (1.f + t);
                    int row = mi * 16 + kq * 4 + j;
                    int byte = row * 2048 + ((col * 2) ^ ((row & 7) << 4));
                    *(f16*)(smem + byte) = (f16)gl;
                }
        }
        WAITLGKM;    // h-writes drained before next barrier
    }
    // ---- fc2 (swapped): out^T[oc][m] += w2 @ h^T ----
    for (int ob = 0; ob < 2; ob++) {
#pragma unroll
        for (int i = 0; i < 8; i++) acc[i] = f32x4{0.f, 0.f, 0.f, 0.f};
#pragma unroll
        for (int ks = 0; ks < 32; ks++) {
            int s = 64 + ob * 32 + ks;
            if (ks == 31) { if (s + 1 < 128) { WAITVM(2); } else { WAITVM(0); } }
            else { WAITVM(2); }
            BAR();
            if (s + 2 < 128) stg(s + 2);
            char* cb = wst + (s % 3) * 8192;
            f16x8 a2[2], bh[4];
#pragma unroll
            for (int ai = 0; ai < 2; ai++) {
                int row = wave * 32 + ai * 16 + lc;
                a2[ai] = *(const f16x8*)(cb + row * 64 + ((kq * 16) ^ ((row & 3) << 4)));
            }
#pragma unroll
            for (int bj = 0; bj < 4; bj++) {
                int row = bj * 16 + lc;
                int byte = row * 2048 + ((ks * 64 + kq * 16) ^ ((row & 7) << 4));
                bh[bj] = *(const f16x8*)(smem + byte);
            }
#pragma unroll
            for (int ai = 0; ai < 2; ai++)
#pragma unroll
                for (int bj = 0; bj < 4; bj++)
                    acc[ai * 4 + bj] = __builtin_amdgcn_mfma_f32_16x16x32_f16(
                        a2[ai], bh[bj], acc[ai * 4 + bj], 0, 0, 0);
        }
#pragma unroll
        for (int ai = 0; ai < 2; ai++) {
            int ocb = ob * 128 + wave * 32 + ai * 16 + kq * 4;
            float4 bb = *(const float4*)&fb2[ocb];
#pragma unroll
            for (int bj = 0; bj < 4; bj++) {
                int m = bj * 16 + lc;
                size_t idx = (size_t)(m0 + m) * 256 + ocb;
                float4 o = *(float4*)&out[idx];
                o.x += acc[ai * 4 + bj][0] + bb.x;
                o.y += acc[ai * 4 + bj][1] + bb.y;
                o.z += acc[ai * 4 + bj][2] + bb.z;
                o.w += acc[ai * 4 + bj][3] + bb.w;
                *(float4*)&out[idx] = o;
            }
        }
    }
}

// One wave per (window, head). Scores/P in LDS [key][query-lane]; K,V staged f32.
__global__ __launch_bounds__(64) void k_attn(const f16* __restrict__ q,
                                             const f16* __restrict__ kk,
                                             const f16* __restrict__ vv,
                                             const float* __restrict__ rpb,
                                             f16* __restrict__ aw, int winbase) {
    __shared__ float kls[64 * 32];
    __shared__ float vls[64 * 32];
    __shared__ float pls[64 * 64];
    __shared__ float rl[225];
    __shared__ int vreg[64];
    const int wl = blockIdx.x >> 3, h = blockIdx.x & 7;
    const int lane = threadIdx.x;
    const size_t base = ((size_t)wl * 8 + h) * 2048;

    {
        const uint4* ks = (const uint4*)(kk + base + lane * 32);
        const uint4* vs = (const uint4*)(vv + base + lane * 32);
#pragma unroll
        for (int c = 0; c < 4; c++) {
            uint4 u = ks[c]; const f16* hp = (const f16*)&u;
#pragma unroll
            for (int e = 0; e < 8; e++) kls[lane * 32 + c * 8 + e] = (float)hp[e];
            uint4 u2 = vs[c]; const f16* hp2 = (const f16*)&u2;
#pragma unroll
            for (int e = 0; e < 8; e++) vls[lane * 32 + c * 8 + e] = (float)hp2[e];
        }
    }
    float qr[32];
    {
        const uint4* qs = (const uint4*)(q + base + lane * 32);
#pragma unroll
        for (int c = 0; c < 4; c++) {
            uint4 u = qs[c]; const f16* hp = (const f16*)&u;
#pragma unroll
            for (int e = 0; e < 8; e++) qr[c * 8 + e] = (float)hp[e];
        }
    }
    for (int i = lane; i < 225; i += 64) rl[i] = rpb[i * 8 + h];
    {
        int gwin = (winbase + wl) & 63;
        int wh = gwin >> 3, ww = gwin & 7;
        int y = lane >> 3, xx = lane & 7;
        int r = (wh < 7) ? 0 : ((y < 4) ? 1 : 2);
        int c = (ww < 7) ? 0 : ((xx < 4) ? 1 : 2);
        vreg[lane] = r * 3 + c;
    }
    __syncthreads();

    const int yi = lane >> 3, xi = lane & 7;
    const int myreg = vreg[lane];
    float mx = -1e30f;
    for (int j = 0; j < 64; j++) {
        const float* kr = &kls[j * 32];
        float a0 = 0.f, a1 = 0.f, a2 = 0.f, a3 = 0.f;
#pragma unroll
        for (int c = 0; c < 32; c += 4) {
            a0 += qr[c] * kr[c];     a1 += qr[c + 1] * kr[c + 1];
            a2 += qr[c + 2] * kr[c + 2]; a3 += qr[c + 3] * kr[c + 3];
        }
        float sc = (a0 + a1) + (a2 + a3);
        int yj = j >> 3, xj = j & 7;
        sc += rl[(yi - yj + 7) * 15 + (xi - xj + 7)];
        if (myreg != vreg[j]) sc -= 100.f;
        pls[j * 64 + lane] = sc;
        mx = fmaxf(mx, sc);
    }
    float sum = 0.f;
    for (int j = 0; j < 64; j++) {
        float e = __expf(pls[j * 64 + lane] - mx);
        pls[j * 64 + lane] = e;
        sum += e;
    }
    float inv = 1.f / sum;
    float o[32];
#pragma unroll
    for (int c = 0; c < 32; c++) o[c] = 0.f;
    for (int j = 0; j < 64; j++) {
        float p = pls[j * 64 + lane];
        const float4* vr = (const float4*)&vls[j * 32];
#pragma unroll
        for (int c = 0; c < 8; c++) {
            float4 v4 = vr[c];
            o[c*4+0] += p * v4.x; o[c*4+1] += p * v4.y;
            o[c*4+2] += p * v4.z; o[c*4+3] += p * v4.w;
        }
    }
    f16 ob[32];
#pragma unroll
    for (int c = 0; c < 32; c++) ob[c] = (f16)(o[c] * inv);
    uint4* dst = (uint4*)(aw + ((size_t)(wl * 64 + lane)) * CC + h * 32);
    const uint4* sp = (const uint4*)ob;
#pragma unroll
    for (int c = 0; c < 4; c++) dst[c] = sp[c];
}

extern "C" void kernel_launch(void* const* d_in, const int* in_sizes, int n_in,
                              void* d_out, int out_size, void* d_ws, size_t ws_size,
                              hipStream_t stream) {
    (void)in_sizes; (void)n_in; (void)out_size; (void)ws_size;
    const float* x      = (const float*)d_in[0];
    const float* g1     = (const float*)d_in[1];
    const float* b1     = (const float*)d_in[2];
    const float* qkv_w  = (const float*)d_in[3];
    const float* qkv_b  = (const float*)d_in[4];
    const float* rpb    = (const float*)d_in[5];
    const float* proj_w = (const float*)d_in[6];
    const float* proj_b = (const float*)d_in[7];
    const float* g2     = (const float*)d_in[8];
    const float* b2     = (const float*)d_in[9];
    const float* fc1_w  = (const float*)d_in[10];
    const float* fc1_b  = (const float*)d_in[11];
    const float* fc2_w  = (const float*)d_in[12];
    const float* fc2_b  = (const float*)d_in[13];
    float* out = (float*)d_out;
    char* ws = (char*)d_ws;
    f16* wq = (f16*)(ws + OFF_WQ);
    f16* wp = (f16*)(ws + OFF_WP);
    f16* w1 = (f16*)(ws + OFF_W1);
    f16* w2 = (f16*)(ws + OFF_W2);
    f16* awb = (f16*)(ws + OFF_R1);
    static constexpr size_t QSZ = (size_t)CWINS * 8 * 64 * 32 * 2; // 16,777,216 B
    f16* hwin = (f16*)(ws + OFF_R2);
    f16* qb   = (f16*)(ws + OFF_R2 + QSZ);
    f16* kb   = (f16*)(ws + OFF_R2 + 2 * QSZ);
    f16* vb   = (f16*)(ws + OFF_R2 + 3 * QSZ);
    f16* m_in = (f16*)(ws + OFF_R2);

    k_cvt<<<768, 256, 0, stream>>>(qkv_w, wq, 768 * 256);
    k_cvt<<<256, 256, 0, stream>>>(proj_w, wp, 256 * 256);
    k_cvt<<<1024, 256, 0, stream>>>(fc1_w, w1, 1024 * 256);
    k_cvt<<<1024, 256, 0, stream>>>(fc2_w, w2, 1024 * 256);

    for (int c = 0; c < ACH; c++) {
        k_ln<<<AROWS / 4, 256, 0, stream>>>(x, g1, b1, hwin, c * AROWS);
        k_qkv<<<dim3(AROWS / 128, 6), 256, 0, stream>>>(
            hwin, wq, qkv_b, qb, kb, vb);
        k_attn<<<CWINS * 8, 64, 0, stream>>>(
            qb, kb, vb, rpb, awb + (size_t)c * AROWS * CC, c * CWINS);
    }
    k_proj<<<ROWS / 64, 256, 0, stream>>>(awb, wp, proj_b, x, out, m_in, g2, b2);

    (void)hipFuncSetAttribute((const void*)k_mlp,
                              hipFuncAttributeMaxDynamicSharedMemorySize, 155648);
    k_mlp<<<ROWS / 64, 256, 155648, stream>>>(m_in, w1, w2, fc1_b, fc2_b, out);
}